// Round 6
// baseline (20.706 us; speedup 1.0000x reference)
//
#include <hip/hip_runtime.h>
#include <math.h>

// Problem constants
#define NB 2          // batch
#define NC 30         // classes
#define NH 4          // heads
#define HWA 13600     // 100*136
#define HWB 3400      // 50*68
#define PNUM 20
// CAP2: candidate buffer. With NT1=1024 each thread-max covers only 12-16
// elements, so tk sits at a lower element-percentile than the 256-thread
// version: expected candidates ~260 (A-level, order-stat estimate), which
// overflowed the old CAP2=256 (round-5 FAIL). 1024 gives ~9-sigma headroom.
#define CAP2 1024
#define NT1 1024      // k1 block size
#define NWV (NT1/64)  // 16 waves per k1 block
#define LOGIT_TH -2.1972245773362196  // ln(0.1/0.9): sigmoid(x)>0.1 <=> x>this

struct Ptrs {
    const float* cls[8];   // [h*2 + l]
    const float* reg[8];   // [h*2 + l]
    const float* anc[2];   // [l]
};

struct Sh {
    unsigned long long candU[CAP2];
    unsigned tw[NWV];
    int cw[NWV];
    int mcnt;
};

__device__ __forceinline__ unsigned f2key(float x) {
    unsigned u = __float_as_uint(x);
    return (u & 0x80000000u) ? ~u : (u | 0x80000000u);
}

// Round-0-proven algorithm, widened to 1024 threads (A: NV=4, B: NV=1).
// Threshold guarantee is per-wave and independent of wave count: the wave
// with max t_w has >=20 thread-maxes >= tk, hence >=20 elements >= tk, so
// the 20th-largest element overall is >= tk and {key >= tk} is a superset
// of the exact top-20. Idle threads (f >= N4) keep mk=0 < any real key and
// never enter the candidate pass; partial waves yield t_w=0 which cannot
// raise tk.
template<int HW, int L>
__device__ __forceinline__ void topk_body(Sh& sh, const Ptrs& p, int bid,
                                          float* __restrict__ topv,
                                          int* __restrict__ topi,
                                          int* __restrict__ cnts) {
    constexpr int N4 = HW / 4;
    constexpr int NV = (N4 + NT1 - 1) / NT1;
    int c = bid % NC; int t = bid / NC;
    int n = t % NB;   int h = t / NB;
    int sid = ((h*2 + L)*NB + n)*NC + c;
    const float* base = p.cls[h*2 + L] + (size_t)(n*NC + c) * HW;
    int tid = threadIdx.x, lane = tid & 63, wv = tid >> 6;

    if (tid == 0) sh.mcnt = 0;

    // Single global pass: values live in registers
    float4 v[NV];
    #pragma unroll
    for (int i = 0; i < NV; ++i) {
        int f = tid + i * NT1;
        if (f < N4) v[i] = ((const float4*)base)[f];
    }

    // Per-thread max key + threshold count
    unsigned mk = 0u; int cnt = 0;
    #pragma unroll
    for (int i = 0; i < NV; ++i) {
        int f = tid + i * NT1;
        if (f < N4) {
            float xs[4] = {v[i].x, v[i].y, v[i].z, v[i].w};
            #pragma unroll
            for (int j = 0; j < 4; ++j) {
                cnt += ((double)xs[j] > LOGIT_TH);
                unsigned k = f2key(xs[j]);
                mk = (k > mk) ? k : mk;
            }
        }
    }
    // Reduce cnt across wave
    for (int off = 32; off; off >>= 1) cnt += __shfl_down(cnt, off);
    if (lane == 0) sh.cw[wv] = cnt;

    // In-wave bitonic ascending sort of the 64 thread-max keys
    unsigned s = mk;
    #pragma unroll
    for (int k = 2; k <= 64; k <<= 1) {
        #pragma unroll
        for (int j = k >> 1; j > 0; j >>= 1) {
            unsigned o = __shfl_xor(s, j);
            bool up = ((lane & k) == 0);
            bool lower = ((lane & j) == 0);
            s = (up == lower) ? min(s, o) : max(s, o);
        }
    }
    // 20th largest of this wave's maxes = sorted_asc[64 - PNUM]
    unsigned t_w = __shfl(s, 64 - PNUM);
    if (lane == 0) sh.tw[wv] = t_w;
    __syncthreads();

    if (tid == 0) {
        int total = 0;
        #pragma unroll
        for (int w = 0; w < NWV; ++w) total += sh.cw[w];
        cnts[sid] = total;
    }
    unsigned tk = 0u;
    #pragma unroll
    for (int w = 0; w < NWV; ++w) tk = max(tk, sh.tw[w]);

    // Collect candidates: key >= tk  (guaranteed superset of exact top-20)
    #pragma unroll
    for (int i = 0; i < NV; ++i) {
        int f = tid + i * NT1;
        if (f < N4) {
            float xs[4] = {v[i].x, v[i].y, v[i].z, v[i].w};
            #pragma unroll
            for (int j = 0; j < 4; ++j) {
                unsigned key = f2key(xs[j]);
                if (key >= tk) {
                    int slot = atomicAdd(&sh.mcnt, 1);
                    if (slot < CAP2) {
                        int eidx = f * 4 + j;
                        sh.candU[slot] = ((unsigned long long)key << 32) |
                                         (unsigned)(~(unsigned)eidx);
                    }
                }
            }
        }
    }
    __syncthreads();

    // Exact rank selection: rank = #{candidates with (key,~idx) strictly greater}
    int M = min(sh.mcnt, CAP2);
    if (tid < M) {
        unsigned long long mu = sh.candU[tid];
        int rank = 0;
        for (int m = 0; m < M; ++m) rank += (sh.candU[m] > mu);
        if (rank < PNUM) {
            unsigned key = (unsigned)(mu >> 32);
            unsigned u = (key & 0x80000000u) ? (key ^ 0x80000000u) : ~key;
            topv[sid * PNUM + rank] = __uint_as_float(u);
            topi[sid * PNUM + rank] = (int)~(unsigned)(mu & 0xFFFFFFFFu);
        }
    }
}

__global__ __launch_bounds__(NT1) void k_topk_all(Ptrs p, float* __restrict__ topv,
                                                  int* __restrict__ topi,
                                                  int* __restrict__ cnts) {
    __shared__ Sh sh;
    if (blockIdx.x < NH * NB * NC)
        topk_body<HWA, 0>(sh, p, blockIdx.x, topv, topi, cnts);
    else
        topk_body<HWB, 1>(sh, p, blockIdx.x - NH * NB * NC, topv, topi, cnts);
}

// ---------------- Kernel 2: heads math + gathered decode + output ----------------
// (byte-identical to the round-3-proven k_out)
// grid = 240 blocks: bid = (h*2 + n)*30 + c ; block = 64 threads
__global__ __launch_bounds__(64) void k_out(Ptrs p, const float* __restrict__ topv,
                                            const int* __restrict__ topi,
                                            const int* __restrict__ cnts,
                                            float* __restrict__ out) {
    __shared__ double sm[2 * PNUM];
    __shared__ int    idxs[2 * PNUM];
    __shared__ int    val[2 * PNUM];
    __shared__ double k16[2][16];
    __shared__ int    pk[2];

    int bid = blockIdx.x;
    int c = bid % NC; int t = bid / NC;
    int n = t % NB;   int h = t / NB;
    int tid = threadIdx.x;

    if (tid < 2 * PNUM) {
        int l = tid / PNUM, k = tid % PNUM;
        int sid = ((h*2 + l)*NB + n)*NC + c;
        float x = topv[sid * PNUM + k];
        int  ix = topi[sid * PNUM + k];
        idxs[tid] = ix;
        int v = ((double)x > LOGIT_TH);
        val[tid] = v;
        sm[tid] = v ? sqrt(1.0 / (1.0 + exp(-(double)x))) : -1e30;
    }
    __syncthreads();

    // gather top-1 box (for size), 32 threads: (l, j)
    if (tid < 32) {
        int l = tid / 16, j = tid % 16;
        int hw = l ? HWB : HWA;
        int pos = idxs[l * PNUM];           // argmax index
        const float* reg = p.reg[h*2 + l];
        double r = (double)reg[((size_t)(n*NC*16 + c*16 + j)) * hw + pos];
        const float* anc = p.anc[l];
        double x1 = anc[pos*4+0], y1 = anc[pos*4+1], x2 = anc[pos*4+2], y2 = anc[pos*4+3];
        double kv;
        if (j < 8) kv = r * (x2 - x1) + (x1 + x2) * 0.5;
        else       kv = r * (y2 - y1) + (y1 + y2) * 0.5;
        k16[l][j] = kv;
    }
    __syncthreads();

    if (tid == 0) {
        double best[2], sz[2];
        for (int l = 0; l < 2; ++l) {
            best[l] = sm[l * PNUM];         // NEG if invalid
            double kxmx = -1e300, kxmn = 1e300, kymx = -1e300, kymn = 1e300;
            for (int j = 0; j < 8; ++j) {
                double kx = k16[l][j], ky = k16[l][j + 8];
                kxmx = fmax(kxmx, kx); kxmn = fmin(kxmn, kx);
                kymx = fmax(kymx, ky); kymn = fmin(kymn, ky);
            }
            double s = fmax(kxmx - kxmn, kymx - kymn);
            sz[l] = (best[l] > 0.0) ? s : 0.0;
        }
        int bi = (best[0] >= best[1]) ? 0 : 1;    // argmax, first-max wins
        double box = sz[bi];
        double safe = (box > 0.0) ? box : 1.0;
        double dk0 = log2(safe / 64.0), dk1 = log2(safe / 128.0);
        double e0 = exp(-dk0 * dk0), e1 = exp(-dk1 * dk1);
        double s = e0 + e1;
        int nk0 = (box > 0.0) ? (int)(20.0 * e0 / s + 0.5) : 0;
        int nk1 = (box > 0.0) ? (int)(20.0 * e1 / s + 0.5) : 0;
        int sid0 = ((h*2 + 0)*NB + n)*NC + c;
        int sid1 = ((h*2 + 1)*NB + n)*NC + c;
        pk[0] = min(cnts[sid0], nk0);
        pk[1] = min(cnts[sid1], nk1);
    }
    __syncthreads();

    // write outputs: 40 (l,k) items, 17 floats each
    if (tid < 2 * PNUM) {
        int l = tid / PNUM, k = tid % PNUM;
        int hw = l ? HWB : HWA;
        bool v = (k < pk[l]) && val[tid];
        size_t ob = ((((size_t)((n*NH + h)*NC + c)) * 2 + l) * PNUM + k) * 17;
        float* o = out + ob;
        if (!v) {
            #pragma unroll
            for (int e = 0; e < 17; ++e) o[e] = 0.f;
        } else {
            o[0] = (float)sm[tid];
            int pos = idxs[tid];
            const float* reg = p.reg[h*2 + l];
            const float* anc = p.anc[l];
            double x1 = anc[pos*4+0], y1 = anc[pos*4+1], x2 = anc[pos*4+2], y2 = anc[pos*4+3];
            double wa = x2 - x1, cxa = (x1 + x2) * 0.5;
            double ha = y2 - y1, cya = (y1 + y2) * 0.5;
            size_t rb = ((size_t)(n*NC*16 + c*16)) * hw + pos;
            #pragma unroll
            for (int j = 0; j < 8; ++j)
                o[1 + j] = (float)((double)reg[rb + (size_t)j * hw] * wa + cxa);
            #pragma unroll
            for (int j = 0; j < 8; ++j)
                o[9 + j] = (float)((double)reg[rb + (size_t)(j + 8) * hw] * ha + cya);
        }
    }
}

extern "C" void kernel_launch(void* const* d_in, const int* in_sizes, int n_in,
                              void* d_out, int out_size, void* d_ws, size_t ws_size,
                              hipStream_t stream) {
    Ptrs p;
    for (int h = 0; h < 4; ++h) {
        p.cls[h*2 + 0] = (const float*)d_in[h*4 + 0];
        p.reg[h*2 + 0] = (const float*)d_in[h*4 + 1];
        p.cls[h*2 + 1] = (const float*)d_in[h*4 + 2];
        p.reg[h*2 + 1] = (const float*)d_in[h*4 + 3];
    }
    p.anc[0] = (const float*)d_in[16];
    p.anc[1] = (const float*)d_in[17];

    const int NSER = NH * 2 * NB * NC;  // 480
    float* topv = (float*)d_ws;
    int*   topi = (int*)((char*)d_ws + (size_t)NSER * PNUM * 4);
    int*   cnts = (int*)((char*)d_ws + (size_t)NSER * PNUM * 8);

    k_topk_all<<<NSER, NT1, 0, stream>>>(p, topv, topi, cnts);
    k_out<<<NH * NB * NC, 64, 0, stream>>>(p, topv, topi, cnts, (float*)d_out);
}

// Round 7
// 20.617 us; speedup vs baseline: 1.0043x; 1.0043x over previous
//
#include <hip/hip_runtime.h>
#include <math.h>

// Problem constants
#define NB 2          // batch
#define NC 30         // classes
#define NH 4          // heads
#define HWA 13600     // 100*136
#define HWB 3400      // 50*68
#define PNUM 20
#define CAP2 256
#define NPAIR (NH * NB * NC)      // 240 series
#define NCH 4                     // A-level split into 4 chunks of 3400 elems
#define N4C 850                   // float4s per chunk (A-chunk == whole B level)
#define NSUBA (NPAIR * NCH)       // 960 A-chunk sub-series
#define NSUB  (NSUBA + NPAIR)     // 1200 total sub-series
#define LOGIT_TH -2.1972245773362196  // ln(0.1/0.9): sigmoid(x)>0.1 <=> x>this

struct Ptrs {
    const float* cls[8];   // [h*2 + l]
    const float* reg[8];   // [h*2 + l]
    const float* anc[2];   // [l]
};

struct Sh {
    unsigned long long candU[CAP2];
    unsigned tw[4];
    int cw[4];
    int mcnt;
};

__device__ __forceinline__ unsigned f2key(float x) {
    unsigned u = __float_as_uint(x);
    return (u & 0x80000000u) ? ~u : (u | 0x80000000u);
}

// ---------------- Kernel 1: per-chunk exact top-20 ----------------
// grid = 1200 blocks x 256 threads. bid < 960: A-chunk (pair = bid>>2,
// chunk = bid&3); else B (pair = bid-960). Every block scans exactly 850
// float4s (3400 elems) — uniform duration, proven 256-thread threshold
// structure (thread-max over 12-16 elems -> M ~ 79+-18 << CAP2=256).
// Chunk top-20s are exact, so k2's merged top-20 of the union is exact.
__global__ __launch_bounds__(256) void k_topk_all(Ptrs p, float* __restrict__ topv,
                                                  int* __restrict__ topi,
                                                  int* __restrict__ cnts) {
    __shared__ Sh sh;
    int bid = blockIdx.x;
    const float* base;
    int elemOff;
    {
        int pair, hslot;
        if (bid < NSUBA) {
            pair = bid >> 2; int ch = bid & 3;
            int c = pair % NC; int t = pair / NC;
            int n = t % NB;   int h = t / NB;
            hslot = h*2 + 0;
            base = p.cls[hslot] + (size_t)(n*NC + c) * HWA + (size_t)ch * (N4C * 4);
            elemOff = ch * (N4C * 4);
        } else {
            pair = bid - NSUBA;
            int c = pair % NC; int t = pair / NC;
            int n = t % NB;   int h = t / NB;
            hslot = h*2 + 1;
            base = p.cls[hslot] + (size_t)(n*NC + c) * HWB;
            elemOff = 0;
        }
    }
    int sid2 = bid;
    int tid = threadIdx.x, lane = tid & 63, wv = tid >> 6;

    if (tid == 0) sh.mcnt = 0;

    constexpr int N4 = N4C;                 // 850
    constexpr int NV = (N4 + 255) / 256;    // 4

    // Single global pass: values live in registers
    float4 v[NV];
    #pragma unroll
    for (int i = 0; i < NV; ++i) {
        int f = tid + i * 256;
        if (f < N4) v[i] = ((const float4*)base)[f];
    }

    // Per-thread max key + threshold count
    unsigned mk = 0u; int cnt = 0;
    #pragma unroll
    for (int i = 0; i < NV; ++i) {
        int f = tid + i * 256;
        if (f < N4) {
            float xs[4] = {v[i].x, v[i].y, v[i].z, v[i].w};
            #pragma unroll
            for (int j = 0; j < 4; ++j) {
                cnt += ((double)xs[j] > LOGIT_TH);
                unsigned k = f2key(xs[j]);
                mk = (k > mk) ? k : mk;
            }
        }
    }
    // Reduce cnt across wave
    for (int off = 32; off; off >>= 1) cnt += __shfl_down(cnt, off);
    if (lane == 0) sh.cw[wv] = cnt;

    // In-wave bitonic ascending sort of the 64 thread-max keys
    unsigned s = mk;
    #pragma unroll
    for (int k = 2; k <= 64; k <<= 1) {
        #pragma unroll
        for (int j = k >> 1; j > 0; j >>= 1) {
            unsigned o = __shfl_xor(s, j);
            bool up = ((lane & k) == 0);
            bool lower = ((lane & j) == 0);
            s = (up == lower) ? min(s, o) : max(s, o);
        }
    }
    // 20th largest of this wave's maxes = sorted_asc[64 - PNUM]
    unsigned t_w = __shfl(s, 64 - PNUM);
    if (lane == 0) sh.tw[wv] = t_w;
    __syncthreads();

    if (tid == 0) cnts[sid2] = sh.cw[0] + sh.cw[1] + sh.cw[2] + sh.cw[3];
    unsigned tk = max(max(sh.tw[0], sh.tw[1]), max(sh.tw[2], sh.tw[3]));

    // Collect candidates: key >= tk (superset of chunk top-20: the wave with
    // max t_w contributes >=20 elements >= tk)
    #pragma unroll
    for (int i = 0; i < NV; ++i) {
        int f = tid + i * 256;
        if (f < N4) {
            float xs[4] = {v[i].x, v[i].y, v[i].z, v[i].w};
            #pragma unroll
            for (int j = 0; j < 4; ++j) {
                unsigned key = f2key(xs[j]);
                if (key >= tk) {
                    int slot = atomicAdd(&sh.mcnt, 1);
                    if (slot < CAP2) {
                        int eidx = elemOff + f * 4 + j;   // GLOBAL element index
                        sh.candU[slot] = ((unsigned long long)key << 32) |
                                         (unsigned)(~(unsigned)eidx);
                    }
                }
            }
        }
    }
    __syncthreads();

    // Exact rank selection within the chunk
    int M = min(sh.mcnt, CAP2);
    if (tid < M) {
        unsigned long long mu = sh.candU[tid];
        int rank = 0;
        for (int m = 0; m < M; ++m) rank += (sh.candU[m] > mu);
        if (rank < PNUM) {
            unsigned key = (unsigned)(mu >> 32);
            unsigned u = (key & 0x80000000u) ? (key ^ 0x80000000u) : ~key;
            topv[sid2 * PNUM + rank] = __uint_as_float(u);
            topi[sid2 * PNUM + rank] = (int)~(unsigned)(mu & 0xFFFFFFFFu);
        }
    }
}

// ---------------- Kernel 2: merge chunks + heads math + decode + output ----------------
// grid = 240 blocks x 64 threads
__global__ __launch_bounds__(64) void k_out(Ptrs p, const float* __restrict__ topv,
                                            const int* __restrict__ topi,
                                            const int* __restrict__ cnts,
                                            float* __restrict__ out) {
    __shared__ float  tvA[NCH * PNUM];
    __shared__ int    idxA[NCH * PNUM];
    __shared__ unsigned long long candM[NCH * PNUM];
    __shared__ float  tv2[2 * PNUM];
    __shared__ int    idxs[2 * PNUM];
    __shared__ double sm[2 * PNUM];
    __shared__ int    val[2 * PNUM];
    __shared__ double k16[2][16];
    __shared__ int    pk[2];
    __shared__ int    cnt2[2];

    int pair = blockIdx.x;
    int c = pair % NC; int t = pair / NC;
    int n = t % NB;   int h = t / NB;
    int tid = threadIdx.x;

    // Phase 1: load 80 A-chunk candidates + 20 B entries + counts (L2-resident)
    for (int e = tid; e < NCH * PNUM; e += 64) {
        int ch = e / PNUM, k = e % PNUM;
        int sid2 = pair * NCH + ch;
        float x = topv[sid2 * PNUM + k];
        int  ix = topi[sid2 * PNUM + k];
        tvA[e] = x; idxA[e] = ix;
        candM[e] = ((unsigned long long)f2key(x) << 32) | (unsigned)(~(unsigned)ix);
    }
    if (tid < PNUM) {
        int sid2 = NSUBA + pair;
        tv2[PNUM + tid]  = topv[sid2 * PNUM + tid];
        idxs[PNUM + tid] = topi[sid2 * PNUM + tid];
    }
    if (tid == 0) {
        cnt2[0] = cnts[pair*NCH + 0] + cnts[pair*NCH + 1]
                + cnts[pair*NCH + 2] + cnts[pair*NCH + 3];
        cnt2[1] = cnts[NSUBA + pair];
    }
    __syncthreads();

    // Phase 2: exact A top-20 = rank-select over the 80 chunk winners.
    // Total order (key desc, idx asc) — identical ordering to k1's, so the
    // merged result equals the unchunked exact top-20 (ties included).
    for (int e = tid; e < NCH * PNUM; e += 64) {
        unsigned long long mu = candM[e];
        int rank = 0;
        for (int m = 0; m < NCH * PNUM; ++m) rank += (candM[m] > mu);
        if (rank < PNUM) { tv2[rank] = tvA[e]; idxs[rank] = idxA[e]; }
    }
    __syncthreads();

    // Phase 3: gather top-1 boxes (issue loads first) + sigmoid math (overlaps)
    if (tid < 32) {
        int l = tid / 16, j = tid % 16;
        int hw = l ? HWB : HWA;
        int pos = idxs[l * PNUM];           // argmax index
        const float* reg = p.reg[h*2 + l];
        double r = (double)reg[((size_t)(n*NC*16 + c*16 + j)) * hw + pos];
        const float* anc = p.anc[l];
        double x1 = anc[pos*4+0], y1 = anc[pos*4+1], x2 = anc[pos*4+2], y2 = anc[pos*4+3];
        double kv;
        if (j < 8) kv = r * (x2 - x1) + (x1 + x2) * 0.5;
        else       kv = r * (y2 - y1) + (y1 + y2) * 0.5;
        k16[l][j] = kv;
    }
    if (tid < 2 * PNUM) {
        float x = tv2[tid];
        int v = ((double)x > LOGIT_TH);
        val[tid] = v;
        sm[tid] = v ? sqrt(1.0 / (1.0 + exp(-(double)x))) : -1e30;
    }
    __syncthreads();

    // Phase 4: serial head math
    if (tid == 0) {
        double best[2], sz[2];
        for (int l = 0; l < 2; ++l) {
            best[l] = sm[l * PNUM];         // NEG if invalid
            double kxmx = -1e300, kxmn = 1e300, kymx = -1e300, kymn = 1e300;
            for (int j = 0; j < 8; ++j) {
                double kx = k16[l][j], ky = k16[l][j + 8];
                kxmx = fmax(kxmx, kx); kxmn = fmin(kxmn, kx);
                kymx = fmax(kymx, ky); kymn = fmin(kymn, ky);
            }
            double s = fmax(kxmx - kxmn, kymx - kymn);
            sz[l] = (best[l] > 0.0) ? s : 0.0;
        }
        int bi = (best[0] >= best[1]) ? 0 : 1;    // argmax, first-max wins
        double box = sz[bi];
        double safe = (box > 0.0) ? box : 1.0;
        double dk0 = log2(safe / 64.0), dk1 = log2(safe / 128.0);
        double e0 = exp(-dk0 * dk0), e1 = exp(-dk1 * dk1);
        double s = e0 + e1;
        int nk0 = (box > 0.0) ? (int)(20.0 * e0 / s + 0.5) : 0;
        int nk1 = (box > 0.0) ? (int)(20.0 * e1 / s + 0.5) : 0;
        pk[0] = min(cnt2[0], nk0);
        pk[1] = min(cnt2[1], nk1);
    }
    __syncthreads();

    // Phase 5: write outputs, 40 (l,k) items x 17 floats
    if (tid < 2 * PNUM) {
        int l = tid / PNUM, k = tid % PNUM;
        int hw = l ? HWB : HWA;
        bool v = (k < pk[l]) && val[tid];
        size_t ob = ((((size_t)((n*NH + h)*NC + c)) * 2 + l) * PNUM + k) * 17;
        float* o = out + ob;
        if (!v) {
            #pragma unroll
            for (int e = 0; e < 17; ++e) o[e] = 0.f;
        } else {
            o[0] = (float)sm[tid];
            int pos = idxs[tid];
            const float* reg = p.reg[h*2 + l];
            const float* anc = p.anc[l];
            double x1 = anc[pos*4+0], y1 = anc[pos*4+1], x2 = anc[pos*4+2], y2 = anc[pos*4+3];
            double wa = x2 - x1, cxa = (x1 + x2) * 0.5;
            double ha = y2 - y1, cya = (y1 + y2) * 0.5;
            size_t rb = ((size_t)(n*NC*16 + c*16)) * hw + pos;
            #pragma unroll
            for (int j = 0; j < 8; ++j)
                o[1 + j] = (float)((double)reg[rb + (size_t)j * hw] * wa + cxa);
            #pragma unroll
            for (int j = 0; j < 8; ++j)
                o[9 + j] = (float)((double)reg[rb + (size_t)(j + 8) * hw] * ha + cya);
        }
    }
}

extern "C" void kernel_launch(void* const* d_in, const int* in_sizes, int n_in,
                              void* d_out, int out_size, void* d_ws, size_t ws_size,
                              hipStream_t stream) {
    Ptrs p;
    for (int h = 0; h < 4; ++h) {
        p.cls[h*2 + 0] = (const float*)d_in[h*4 + 0];
        p.reg[h*2 + 0] = (const float*)d_in[h*4 + 1];
        p.cls[h*2 + 1] = (const float*)d_in[h*4 + 2];
        p.reg[h*2 + 1] = (const float*)d_in[h*4 + 3];
    }
    p.anc[0] = (const float*)d_in[16];
    p.anc[1] = (const float*)d_in[17];

    // Workspace: topv[NSUB*20] f32, topi[NSUB*20] i32, cnts[NSUB] i32 (~197 KB)
    float* topv = (float*)d_ws;
    int*   topi = (int*)((char*)d_ws + (size_t)NSUB * PNUM * 4);
    int*   cnts = (int*)((char*)d_ws + (size_t)NSUB * PNUM * 8);

    k_topk_all<<<NSUB, 256, 0, stream>>>(p, topv, topi, cnts);
    k_out<<<NPAIR, 64, 0, stream>>>(p, topv, topi, cnts, (float*)d_out);
}

// Round 8
// 18.890 us; speedup vs baseline: 1.0961x; 1.0914x over previous
//
#include <hip/hip_runtime.h>
#include <hip/hip_bf16.h>
#include <math.h>

// Problem constants
#define NB 2          // batch
#define NC 30         // classes
#define NH 4          // heads
#define HWA 13600     // 100*136
#define HWB 3400      // 50*68
#define PNUM 20
#define CAP2 256
#define LOGIT_TH -2.1972245773362196  // ln(0.1/0.9): sigmoid(x)>0.1 <=> x>this

// Session-proven optimum (18.5/18.76/18.9 us across three identical-source runs).
// Structural variants all regress: block-fusion +2.8, eager-gather epilogue +5.2,
// 1024-thread k1 +2.2, 4-way chunked k1 +2.1, last-arriver single-kernel FAIL
// (workspace flags not zero-initialized). Residual time is fixed graph/launch
// overhead, invariant under source-level change.

struct Ptrs {
    const float* cls[8];   // [h*2 + l]
    const float* reg[8];   // [h*2 + l]
    const float* anc[2];   // [l]
};

struct Sh {
    unsigned long long candU[CAP2];
    unsigned tw[4];
    int cw[4];
    int mcnt;
};

__device__ __forceinline__ unsigned f2key(float x) {
    unsigned u = __float_as_uint(x);
    return (u & 0x80000000u) ? ~u : (u | 0x80000000u);
}

template<int HW, int L>
__device__ __forceinline__ void topk_body(Sh& sh, const Ptrs& p, int bid,
                                          float* __restrict__ topv,
                                          int* __restrict__ topi,
                                          int* __restrict__ cnts) {
    constexpr int N4 = HW / 4;
    constexpr int NV = (N4 + 255) / 256;
    int c = bid % NC; int t = bid / NC;
    int n = t % NB;   int h = t / NB;
    int sid = ((h*2 + L)*NB + n)*NC + c;
    const float* base = p.cls[h*2 + L] + (size_t)(n*NC + c) * HW;
    int tid = threadIdx.x, lane = tid & 63, wv = tid >> 6;

    if (tid == 0) sh.mcnt = 0;

    // Single global pass: values live in registers
    float4 v[NV];
    #pragma unroll
    for (int i = 0; i < NV; ++i) {
        int f = tid + i * 256;
        if (f < N4) v[i] = ((const float4*)base)[f];
    }

    // Per-thread max key + threshold count
    unsigned mk = 0u; int cnt = 0;
    #pragma unroll
    for (int i = 0; i < NV; ++i) {
        int f = tid + i * 256;
        if (f < N4) {
            float xs[4] = {v[i].x, v[i].y, v[i].z, v[i].w};
            #pragma unroll
            for (int j = 0; j < 4; ++j) {
                cnt += ((double)xs[j] > LOGIT_TH);
                unsigned k = f2key(xs[j]);
                mk = (k > mk) ? k : mk;
            }
        }
    }
    // Reduce cnt across wave
    for (int off = 32; off; off >>= 1) cnt += __shfl_down(cnt, off);
    if (lane == 0) sh.cw[wv] = cnt;

    // In-wave bitonic ascending sort of the 64 thread-max keys
    unsigned s = mk;
    #pragma unroll
    for (int k = 2; k <= 64; k <<= 1) {
        #pragma unroll
        for (int j = k >> 1; j > 0; j >>= 1) {
            unsigned o = __shfl_xor(s, j);
            bool up = ((lane & k) == 0);
            bool lower = ((lane & j) == 0);
            s = (up == lower) ? min(s, o) : max(s, o);
        }
    }
    // 20th largest of this wave's maxes = sorted_asc[64 - PNUM]
    unsigned t_w = __shfl(s, 64 - PNUM);
    if (lane == 0) sh.tw[wv] = t_w;
    __syncthreads();

    if (tid == 0) cnts[sid] = sh.cw[0] + sh.cw[1] + sh.cw[2] + sh.cw[3];
    unsigned tk = max(max(sh.tw[0], sh.tw[1]), max(sh.tw[2], sh.tw[3]));

    // Collect candidates: key >= tk  (guaranteed superset of exact top-20)
    #pragma unroll
    for (int i = 0; i < NV; ++i) {
        int f = tid + i * 256;
        if (f < N4) {
            float xs[4] = {v[i].x, v[i].y, v[i].z, v[i].w};
            #pragma unroll
            for (int j = 0; j < 4; ++j) {
                unsigned key = f2key(xs[j]);
                if (key >= tk) {
                    int slot = atomicAdd(&sh.mcnt, 1);
                    if (slot < CAP2) {
                        int eidx = f * 4 + j;
                        sh.candU[slot] = ((unsigned long long)key << 32) |
                                         (unsigned)(~(unsigned)eidx);
                    }
                }
            }
        }
    }
    __syncthreads();

    // Exact rank selection: rank = #{candidates with (key,~idx) strictly greater}
    int M = min(sh.mcnt, CAP2);
    if (tid < M) {
        unsigned long long mu = sh.candU[tid];
        int rank = 0;
        for (int m = 0; m < M; ++m) rank += (sh.candU[m] > mu);
        if (rank < PNUM) {
            unsigned key = (unsigned)(mu >> 32);
            unsigned u = (key & 0x80000000u) ? (key ^ 0x80000000u) : ~key;
            topv[sid * PNUM + rank] = __uint_as_float(u);
            topi[sid * PNUM + rank] = (int)~(unsigned)(mu & 0xFFFFFFFFu);
        }
    }
}

__global__ __launch_bounds__(256) void k_topk_all(Ptrs p, float* __restrict__ topv,
                                                  int* __restrict__ topi,
                                                  int* __restrict__ cnts) {
    __shared__ Sh sh;
    if (blockIdx.x < NH * NB * NC)
        topk_body<HWA, 0>(sh, p, blockIdx.x, topv, topi, cnts);
    else
        topk_body<HWB, 1>(sh, p, blockIdx.x - NH * NB * NC, topv, topi, cnts);
}

// ---------------- Kernel 2: heads math + gathered decode + output ----------------
// grid = 240 blocks: bid = (h*2 + n)*30 + c ; block = 64 threads
__global__ __launch_bounds__(64) void k_out(Ptrs p, const float* __restrict__ topv,
                                            const int* __restrict__ topi,
                                            const int* __restrict__ cnts,
                                            float* __restrict__ out) {
    __shared__ double sm[2 * PNUM];
    __shared__ int    idxs[2 * PNUM];
    __shared__ int    val[2 * PNUM];
    __shared__ double k16[2][16];
    __shared__ int    pk[2];

    int bid = blockIdx.x;
    int c = bid % NC; int t = bid / NC;
    int n = t % NB;   int h = t / NB;
    int tid = threadIdx.x;

    if (tid < 2 * PNUM) {
        int l = tid / PNUM, k = tid % PNUM;
        int sid = ((h*2 + l)*NB + n)*NC + c;
        float x = topv[sid * PNUM + k];
        int  ix = topi[sid * PNUM + k];
        idxs[tid] = ix;
        int v = ((double)x > LOGIT_TH);
        val[tid] = v;
        sm[tid] = v ? sqrt(1.0 / (1.0 + exp(-(double)x))) : -1e30;
    }
    __syncthreads();

    // gather top-1 box (for size), 32 threads: (l, j)
    if (tid < 32) {
        int l = tid / 16, j = tid % 16;
        int hw = l ? HWB : HWA;
        int pos = idxs[l * PNUM];           // argmax index
        const float* reg = p.reg[h*2 + l];
        double r = (double)reg[((size_t)(n*NC*16 + c*16 + j)) * hw + pos];
        const float* anc = p.anc[l];
        double x1 = anc[pos*4+0], y1 = anc[pos*4+1], x2 = anc[pos*4+2], y2 = anc[pos*4+3];
        double kv;
        if (j < 8) kv = r * (x2 - x1) + (x1 + x2) * 0.5;
        else       kv = r * (y2 - y1) + (y1 + y2) * 0.5;
        k16[l][j] = kv;
    }
    __syncthreads();

    if (tid == 0) {
        double best[2], sz[2];
        for (int l = 0; l < 2; ++l) {
            best[l] = sm[l * PNUM];         // NEG if invalid
            double kxmx = -1e300, kxmn = 1e300, kymx = -1e300, kymn = 1e300;
            for (int j = 0; j < 8; ++j) {
                double kx = k16[l][j], ky = k16[l][j + 8];
                kxmx = fmax(kxmx, kx); kxmn = fmin(kxmn, kx);
                kymx = fmax(kymx, ky); kymn = fmin(kymn, ky);
            }
            double s = fmax(kxmx - kxmn, kymx - kymn);
            sz[l] = (best[l] > 0.0) ? s : 0.0;
        }
        int bi = (best[0] >= best[1]) ? 0 : 1;    // argmax, first-max wins
        double box = sz[bi];
        double safe = (box > 0.0) ? box : 1.0;
        double dk0 = log2(safe / 64.0), dk1 = log2(safe / 128.0);
        double e0 = exp(-dk0 * dk0), e1 = exp(-dk1 * dk1);
        double s = e0 + e1;
        int nk0 = (box > 0.0) ? (int)(20.0 * e0 / s + 0.5) : 0;
        int nk1 = (box > 0.0) ? (int)(20.0 * e1 / s + 0.5) : 0;
        int sid0 = ((h*2 + 0)*NB + n)*NC + c;
        int sid1 = ((h*2 + 1)*NB + n)*NC + c;
        pk[0] = min(cnts[sid0], nk0);
        pk[1] = min(cnts[sid1], nk1);
    }
    __syncthreads();

    // write outputs: 40 (l,k) items, 17 floats each
    if (tid < 2 * PNUM) {
        int l = tid / PNUM, k = tid % PNUM;
        int hw = l ? HWB : HWA;
        bool v = (k < pk[l]) && val[tid];
        size_t ob = ((((size_t)((n*NH + h)*NC + c)) * 2 + l) * PNUM + k) * 17;
        float* o = out + ob;
        if (!v) {
            #pragma unroll
            for (int e = 0; e < 17; ++e) o[e] = 0.f;
        } else {
            o[0] = (float)sm[tid];
            int pos = idxs[tid];
            const float* reg = p.reg[h*2 + l];
            const float* anc = p.anc[l];
            double x1 = anc[pos*4+0], y1 = anc[pos*4+1], x2 = anc[pos*4+2], y2 = anc[pos*4+3];
            double wa = x2 - x1, cxa = (x1 + x2) * 0.5;
            double ha = y2 - y1, cya = (y1 + y2) * 0.5;
            size_t rb = ((size_t)(n*NC*16 + c*16)) * hw + pos;
            #pragma unroll
            for (int j = 0; j < 8; ++j)
                o[1 + j] = (float)((double)reg[rb + (size_t)j * hw] * wa + cxa);
            #pragma unroll
            for (int j = 0; j < 8; ++j)
                o[9 + j] = (float)((double)reg[rb + (size_t)(j + 8) * hw] * ha + cya);
        }
    }
}

extern "C" void kernel_launch(void* const* d_in, const int* in_sizes, int n_in,
                              void* d_out, int out_size, void* d_ws, size_t ws_size,
                              hipStream_t stream) {
    Ptrs p;
    for (int h = 0; h < 4; ++h) {
        p.cls[h*2 + 0] = (const float*)d_in[h*4 + 0];
        p.reg[h*2 + 0] = (const float*)d_in[h*4 + 1];
        p.cls[h*2 + 1] = (const float*)d_in[h*4 + 2];
        p.reg[h*2 + 1] = (const float*)d_in[h*4 + 3];
    }
    p.anc[0] = (const float*)d_in[16];
    p.anc[1] = (const float*)d_in[17];

    const int NSER = NH * 2 * NB * NC;  // 480
    float* topv = (float*)d_ws;
    int*   topi = (int*)((char*)d_ws + (size_t)NSER * PNUM * 4);
    int*   cnts = (int*)((char*)d_ws + (size_t)NSER * PNUM * 8);

    k_topk_all<<<NSER, 256, 0, stream>>>(p, topv, topi, cnts);
    k_out<<<NH * NB * NC, 64, 0, stream>>>(p, topv, topi, cnts, (float*)d_out);
}